// Round 7
// baseline (65425.580 us; speedup 1.0000x reference)
//
#include <hip/hip_runtime.h>
#include <hip/hip_bf16.h>

#define HDIM 96
#define G4   384
#define LSEQ 32768
#define BATCH 8

__device__ __forceinline__ float RDL(float v, int l) {
    return __uint_as_float(__builtin_amdgcn_readlane(__float_as_uint(v), l));
}
__device__ __forceinline__ float tanh_(float x) { return 2.f / (1.f + __expf(-2.f * x)) - 1.f; }

// 12 named float4 per thread = 48 weight floats (half a gate row).
// Need ~75 VGPRs total -> below every grant the allocator has ever given us.
#define W12(F) F(0) F(1) F(2) F(3) F(4) F(5) F(6) F(7) F(8) F(9) F(10) F(11)
#define WDECL(n) float4 w_##n;
#define WLOAD(n) w_##n = Wp[n];
#define WPIN(n)  asm volatile("" : "+v"(w_##n.x), "+v"(w_##n.y), "+v"(w_##n.z), "+v"(w_##n.w));

// Branchless half-row matvec: every wave's hU holds h[base+lane], so both
// column halves use the identical lane pattern 0..47.
#define MV(n) { \
    float h0_=RDL(hU,4*n+0), h1_=RDL(hU,4*n+1), h2_=RDL(hU,4*n+2), h3_=RDL(hU,4*n+3); \
    a0=fmaf(w_##n.x,h0_,a0); a1=fmaf(w_##n.y,h1_,a1); \
    a2=fmaf(w_##n.z,h2_,a2); a3=fmaf(w_##n.w,h3_,a3); }
#define MV_ALL() MV(0) MV(1) MV(2) MV(3) MV(4) MV(5) MV(6) MV(7) MV(8) MV(9) MV(10) MV(11)

// ---------------------------------------------------------------------------
// Scan: 768 threads (12 waves). Thread tid<384 owns row tid, cols 0..47;
// thread tid>=384 owns row tid-384, cols 48..95. High threads publish their
// partial; low threads combine+activate; every wave redundantly updates the
// c/h elements it broadcasts (hU = h[base+lane], base=0 waves 0-5, 48 for
// waves 6-11). Two barriers/step, no h LDS round-trip on the critical path.
// ---------------------------------------------------------------------------
__global__ void __launch_bounds__(768)
__attribute__((amdgpu_waves_per_eu(3, 3)))
lstm_layer0(const float* __restrict__ x,
            const float* __restrict__ Wih,
            const float* __restrict__ Whh,
            const float* __restrict__ bvec,
            const float* __restrict__ h0v,
            const float* __restrict__ c0v,
            float* __restrict__ hout)
{
    const int bidx = blockIdx.x;
    const int tid  = threadIdx.x;
    const int lane = tid & 63;
    const int wid  = tid >> 6;
    const bool lo  = (tid < G4);
    const int row  = lo ? tid : tid - G4;
    const int cbase = lo ? 0 : 48;
    const int hbase = (wid < 6) ? 0 : 48;

    __shared__ float part_sh[G4];
    __shared__ float gates_sh[G4];

    const float4* Wp = reinterpret_cast<const float4*>(Whh + row * HDIM + cbase);
    W12(WDECL) W12(WLOAD) W12(WPIN)

    float wi = 0.f, bb = 0.f;
    if (lo) { wi = Wih[row]; bb = bvec[row]; }
    const bool isTanh = lo && (row >= 192) && (row < 288);

    const int e = (hbase + lane > 95) ? 95 : (hbase + lane);  // clamped h index
    float hU = h0v[e];
    float cU = c0v[e];

    const float* xb  = x + (size_t)bidx * LSEQ;
    float*       hob = hout + (size_t)bidx * LSEQ * HDIM;
    float xt = xb[0];

#pragma unroll 1
    for (int t = 0; t < LSEQ; ++t) {
        float xnext = (t + 1 < LSEQ) ? xb[t + 1] : 0.f;

        float a0 = lo ? fmaf(wi, xt, bb) : 0.f;
        float a1 = 0.f, a2 = 0.f, a3 = 0.f;
        MV_ALL()
        float part = (a0 + a1) + (a2 + a3);

        if (!lo) part_sh[row] = part;
        __syncthreads();
        if (lo) {
            float g = part + part_sh[row];
            float arg = isTanh ? (-2.f * g) : (-g);
            float r = 1.f / (1.f + __expf(arg));
            gates_sh[row] = isTanh ? (2.f * r - 1.f) : r;
        }
        __syncthreads();

        float si = gates_sh[e];
        float sf = gates_sh[96 + e];
        float tg = gates_sh[192 + e];
        float so = gates_sh[288 + e];
        cU = fmaf(sf, cU, si * tg);
        hU = so * tanh_(cU);

        if (wid == 0)                                  hob[(size_t)t * HDIM + lane] = hU;
        else if (wid == 6 && lane >= 16 && lane < 48)  hob[(size_t)t * HDIM + 48 + lane] = hU;

        xt = xnext;
    }
}

__global__ void __launch_bounds__(768)
__attribute__((amdgpu_waves_per_eu(3, 3)))
lstm_layer1(const float* __restrict__ xp,     // (B,T,384), bias folded
            const float* __restrict__ Whh,
            const float* __restrict__ h0v,
            const float* __restrict__ c0v,
            float* __restrict__ carry,        // (B,192): h[0..95], c[96..191]
            float* __restrict__ h1out,        // (B,T,96)
            int chunk, int T)
{
    const int bidx = blockIdx.x;
    const int tid  = threadIdx.x;
    const int lane = tid & 63;
    const int wid  = tid >> 6;
    const bool lo  = (tid < G4);
    const int row  = lo ? tid : tid - G4;
    const int cbase = lo ? 0 : 48;
    const int hbase = (wid < 6) ? 0 : 48;

    __shared__ float part_sh[G4];
    __shared__ float gates_sh[G4];

    const float4* Wp = reinterpret_cast<const float4*>(Whh + row * HDIM + cbase);
    W12(WDECL) W12(WLOAD) W12(WPIN)

    const bool isTanh = lo && (row >= 192) && (row < 288);

    float* cb = carry + bidx * 2 * HDIM;
    const int e = (hbase + lane > 95) ? 95 : (hbase + lane);
    float hU, cU;
    if (chunk == 0) { hU = h0v[HDIM + e]; cU = c0v[HDIM + e]; }
    else            { hU = cb[e];         cU = cb[HDIM + e]; }

    const float* xpb = xp + (size_t)bidx * T * G4;
    float*       hb1 = h1out + (size_t)bidx * T * HDIM;

    float xc = lo ? xpb[tid] : 0.f;

#pragma unroll 1
    for (int t = 0; t < T; ++t) {
        float xn = 0.f;
        if (lo && (t + 1 < T)) xn = xpb[(size_t)(t + 1) * G4 + tid];

        float a0 = lo ? xc : 0.f;
        float a1 = 0.f, a2 = 0.f, a3 = 0.f;
        MV_ALL()
        float part = (a0 + a1) + (a2 + a3);

        if (!lo) part_sh[row] = part;
        __syncthreads();
        if (lo) {
            float g = part + part_sh[row];
            float arg = isTanh ? (-2.f * g) : (-g);
            float r = 1.f / (1.f + __expf(arg));
            gates_sh[row] = isTanh ? (2.f * r - 1.f) : r;
        }
        __syncthreads();

        float si = gates_sh[e];
        float sf = gates_sh[96 + e];
        float tg = gates_sh[192 + e];
        float so = gates_sh[288 + e];
        cU = fmaf(sf, cU, si * tg);
        hU = so * tanh_(cU);

        if (wid == 0)                                  hb1[(size_t)t * HDIM + lane] = hU;
        else if (wid == 6 && lane >= 16 && lane < 48)  hb1[(size_t)t * HDIM + 48 + lane] = hU;

        xc = xn;
    }

    if (wid == 0) { cb[lane] = hU; cb[HDIM + lane] = cU; }
    else if (wid == 6 && lane >= 16 && lane < 48) {
        cb[48 + lane] = hU; cb[HDIM + 48 + lane] = cU;
    }
}

// ---------------------------------------------------------------------------
// Layer-1 input projection (parallel over timesteps), bias folded in.
// ---------------------------------------------------------------------------
#define W24(F) F(0) F(1) F(2) F(3) F(4) F(5) F(6) F(7) F(8) F(9) F(10) F(11) \
               F(12) F(13) F(14) F(15) F(16) F(17) F(18) F(19) F(20) F(21) F(22) F(23)

__global__ __launch_bounds__(384, 1)
void xp_gemm(const float* __restrict__ hin,
             const float* __restrict__ Wih,
             const float* __restrict__ bvec,
             float* __restrict__ xp,
             int t0, int T)
{
    const int TT = 32;
    const int ntb = T / TT;
    const int b  = blockIdx.x / ntb;
    const int tb = blockIdx.x % ntb;
    const int g  = threadIdx.x;

    __shared__ __align__(16) float h_sh[TT * HDIM];

    const float4* W0p = reinterpret_cast<const float4*>(Wih + g * HDIM);
#define XDECL(n) float4 v_##n;
#define XLOAD(n) v_##n = W0p[n];
    W24(XDECL)
    W24(XLOAD)
    const float bias = bvec[g];

    const float* src = hin + ((size_t)b * LSEQ + t0 + (size_t)tb * TT) * HDIM;
    for (int i = g; i < TT * HDIM; i += G4) h_sh[i] = src[i];
    __syncthreads();

    float* dst = xp + ((size_t)b * T + (size_t)tb * TT) * G4 + g;
    for (int tt = 0; tt < TT; ++tt) {
        const float4* h4 = reinterpret_cast<const float4*>(h_sh + tt * HDIM);
        float acc0 = bias, acc1 = 0.f, acc2 = 0.f, acc3 = 0.f;
#define XFMA(n) { float4 hv = h4[n]; \
        acc0 = fmaf(v_##n.x, hv.x, acc0); acc1 = fmaf(v_##n.y, hv.y, acc1); \
        acc2 = fmaf(v_##n.z, hv.z, acc2); acc3 = fmaf(v_##n.w, hv.w, acc3); }
        W24(XFMA)
        dst[(size_t)tt * G4] = (acc0 + acc1) + (acc2 + acc3);
    }
}

// ---------------------------------------------------------------------------
// Head GEMV: out[b][t] = h1[b][t][:] . head_w + head_b
// ---------------------------------------------------------------------------
__global__ __launch_bounds__(256, 1)
void head_gemv(const float* __restrict__ h1,
               const float* __restrict__ head_w,
               const float* __restrict__ head_b,
               float* __restrict__ out,
               int chunk, int T)
{
    const int idx  = blockIdx.x * 4 + (threadIdx.x >> 6);
    const int lane = threadIdx.x & 63;
    const int b = idx / T;
    const int t = idx % T;

    const float* hp = h1 + ((size_t)b * T + t) * HDIM;
    float s = hp[lane] * head_w[lane];
    if (lane < 32) s = fmaf(hp[64 + lane], head_w[64 + lane], s);
    s += __shfl_down(s, 32);
    s += __shfl_down(s, 16);
    s += __shfl_down(s, 8);
    s += __shfl_down(s, 4);
    s += __shfl_down(s, 2);
    s += __shfl_down(s, 1);
    if (lane == 0) out[(size_t)b * LSEQ + (size_t)chunk * T + t] = s + head_b[0];
}

// ---------------------------------------------------------------------------
extern "C" void kernel_launch(void* const* d_in, const int* in_sizes, int n_in,
                              void* d_out, int out_size, void* d_ws, size_t ws_size,
                              hipStream_t stream)
{
    const float* x     = (const float*)d_in[0];
    const float* Wih0  = (const float*)d_in[1];
    const float* Whh0  = (const float*)d_in[2];
    const float* b0    = (const float*)d_in[3];
    const float* Wih1  = (const float*)d_in[4];
    const float* Whh1  = (const float*)d_in[5];
    const float* b1    = (const float*)d_in[6];
    const float* h0    = (const float*)d_in[7];
    const float* c0    = (const float*)d_in[8];
    const float* headw = (const float*)d_in[9];
    const float* headb = (const float*)d_in[10];
    float* out = (float*)d_out;

    char* ws = (char*)d_ws;
    const size_t h0bytes = (size_t)BATCH * LSEQ * HDIM * sizeof(float); // 100.7 MB

    int T = 4096;
    while (T > 512) {
        size_t need = h0bytes
                    + (size_t)T * BATCH * G4 * sizeof(float)
                    + (size_t)T * BATCH * HDIM * sizeof(float)
                    + 8192;
        if (need <= ws_size) break;
        T >>= 1;
    }

    float* h0buf = (float*)ws;
    float* xpbuf = (float*)(ws + h0bytes);
    float* h1buf = (float*)(ws + h0bytes + (size_t)T * BATCH * G4 * sizeof(float));
    float* carry = (float*)(ws + h0bytes + (size_t)T * BATCH * G4 * sizeof(float)
                               + (size_t)T * BATCH * HDIM * sizeof(float));

    lstm_layer0<<<BATCH, 768, 0, stream>>>(x, Wih0, Whh0, b0, h0, c0, h0buf);

    const int nch = LSEQ / T;
    for (int ch = 0; ch < nch; ++ch) {
        xp_gemm<<<BATCH * (T / 32), G4, 0, stream>>>(h0buf, Wih1, b1, xpbuf, ch * T, T);
        lstm_layer1<<<BATCH, 768, 0, stream>>>(xpbuf, Whh1, h0, c0, carry, h1buf, ch, T);
        head_gemv<<<BATCH * T / 4, 256, 0, stream>>>(h1buf, headw, headb, out, ch, T);
    }
}

// Round 8
// 53330.243 us; speedup vs baseline: 1.2268x; 1.2268x over previous
//
#include <hip/hip_runtime.h>
#include <hip/hip_bf16.h>

#define HDIM 96
#define G4   384
#define LSEQ 32768
#define BATCH 8

__device__ __forceinline__ float RDL(float v, int l) {
    return __uint_as_float(__builtin_amdgcn_readlane(__float_as_uint(v), l));
}
__device__ __forceinline__ float tanh_(float x) { return 2.f / (1.f + __expf(-2.f * x)) - 1.f; }

// Per thread: row-pair (rp, rp+192) x 24 columns = 48 weights = 12 float4.
// Fits the ~68-VGPR grant the allocator gives 768-thread blocks (round 7
// proved residency at this footprint). Each readlane feeds 4 FMAs.
#define W6(F) F(0) F(1) F(2) F(3) F(4) F(5)
#define WDECL(n) float4 wA_##n, wB_##n;
#define WLOAD(n) wA_##n = WA[n]; wB_##n = WB[n];
#define WPIN(n)  asm volatile("" : "+v"(wA_##n.x), "+v"(wA_##n.y), "+v"(wA_##n.z), "+v"(wA_##n.w), \
                                   "+v"(wB_##n.x), "+v"(wB_##n.y), "+v"(wB_##n.z), "+v"(wB_##n.w));

// hU holds h[cs + lane] (lanes 0..23 valid); uniform lane indices 0..23.
#define MV(n) { \
    float h0_=RDL(hU,4*n+0), h1_=RDL(hU,4*n+1), h2_=RDL(hU,4*n+2), h3_=RDL(hU,4*n+3); \
    a0  = fmaf(wA_##n.x, h0_, a0);  a1  = fmaf(wB_##n.x, h0_, a1); \
    a0b = fmaf(wA_##n.y, h1_, a0b); a1b = fmaf(wB_##n.y, h1_, a1b); \
    a0  = fmaf(wA_##n.z, h2_, a0);  a1  = fmaf(wB_##n.z, h2_, a1); \
    a0b = fmaf(wA_##n.w, h3_, a0b); a1b = fmaf(wB_##n.w, h3_, a1b); }
#define MV_ALL() MV(0) MV(1) MV(2) MV(3) MV(4) MV(5)

// ---------------------------------------------------------------------------
// Scan: 768 threads (12 waves). wid/3 = column segment (0..3, 24 cols each);
// rp = (wid%3)*64+lane = row-pair (0..191) -> rows (rp, rp+192).
//   rp<96  : (i_rp, g_rp)   -> combiner publishes p = sig(i)*tanh(g)
//   rp>=96 : (f_e, o_e)     -> combiner publishes (sig f, sig o), e=rp-96
// Column-segment-0 threads (tid<192, rp==tid) keep their partial in regs,
// read 3 LDS partials, activate. All waves redundantly update the c/h
// elements they broadcast (hU = h[cs+lane]); h never leaves registers.
// ---------------------------------------------------------------------------
__global__ void __launch_bounds__(768)
__attribute__((amdgpu_waves_per_eu(3, 3)))
lstm_layer0(const float* __restrict__ x,
            const float* __restrict__ Wih,
            const float* __restrict__ Whh,
            const float* __restrict__ bvec,
            const float* __restrict__ h0v,
            const float* __restrict__ c0v,
            float* __restrict__ hout)
{
    const int bidx  = blockIdx.x;
    const int tid   = threadIdx.x;
    const int lane  = tid & 63;
    const int wid   = tid >> 6;
    const int colseg = wid / 3;                 // 0..3
    const int rp    = (wid % 3) * 64 + lane;    // 0..191
    const int cs    = colseg * 24;
    const bool comb = (wid < 3);                // combiner threads: rp == tid

    __shared__ float2 part_sh[3][192];
    __shared__ float  p_sh[96];
    __shared__ float2 fo_sh[96];

    const float4* WA = reinterpret_cast<const float4*>(Whh + rp * HDIM + cs);
    const float4* WB = reinterpret_cast<const float4*>(Whh + (rp + 192) * HDIM + cs);
    W6(WDECL) W6(WLOAD) W6(WPIN)

    float bb0 = 0.f, bb1 = 0.f, wi0 = 0.f, wi1 = 0.f;
    if (comb) { bb0 = bvec[rp]; bb1 = bvec[rp + 192]; wi0 = Wih[rp]; wi1 = Wih[rp + 192]; }

    const int e = cs + ((lane < 24) ? lane : 23);
    float hU = h0v[e];
    float cU = c0v[e];

    const float* xb  = x + (size_t)bidx * LSEQ;
    float*       hob = hout + (size_t)bidx * LSEQ * HDIM;
    float xt = xb[0];
    const bool hstore = ((wid % 3) == 0) && (lane < 24);

#pragma unroll 1
    for (int t = 0; t < LSEQ; ++t) {
        float xnext = (t + 1 < LSEQ) ? xb[t + 1] : 0.f;

        float a0, a1;
        if (comb) { a0 = fmaf(wi0, xt, bb0); a1 = fmaf(wi1, xt, bb1); }
        else      { a0 = 0.f; a1 = 0.f; }
        float a0b = 0.f, a1b = 0.f;
        MV_ALL()
        float g0 = a0 + a0b;
        float g1 = a1 + a1b;

        if (!comb) part_sh[colseg - 1][rp] = make_float2(g0, g1);
        __syncthreads();

        if (comb) {
            float2 q0 = part_sh[0][rp], q1 = part_sh[1][rp], q2 = part_sh[2][rp];
            g0 += (q0.x + q1.x) + q2.x;
            g1 += (q0.y + q1.y) + q2.y;
            float s0 = 1.f / (1.f + __expf(-g0));
            if (rp < 96) {
                float tg = 2.f / (1.f + __expf(-2.f * g1)) - 1.f;
                p_sh[rp] = s0 * tg;
            } else {
                float s1 = 1.f / (1.f + __expf(-g1));
                fo_sh[rp - 96] = make_float2(s0, s1);
            }
        }
        __syncthreads();

        float  p  = p_sh[e];
        float2 fo = fo_sh[e];
        cU = fmaf(fo.x, cU, p);
        hU = fo.y * tanh_(cU);

        if (hstore) hob[(size_t)t * HDIM + e] = hU;
        xt = xnext;
    }
}

__global__ void __launch_bounds__(768)
__attribute__((amdgpu_waves_per_eu(3, 3)))
lstm_layer1(const float* __restrict__ xp,     // (B,T,384), bias folded
            const float* __restrict__ Whh,
            const float* __restrict__ h0v,
            const float* __restrict__ c0v,
            float* __restrict__ carry,        // (B,192): h[0..95], c[96..191]
            float* __restrict__ h1out,        // (B,T,96)
            int chunk, int T)
{
    const int bidx  = blockIdx.x;
    const int tid   = threadIdx.x;
    const int lane  = tid & 63;
    const int wid   = tid >> 6;
    const int colseg = wid / 3;
    const int rp    = (wid % 3) * 64 + lane;
    const int cs    = colseg * 24;
    const bool comb = (wid < 3);

    __shared__ float2 part_sh[3][192];
    __shared__ float  p_sh[96];
    __shared__ float2 fo_sh[96];

    const float4* WA = reinterpret_cast<const float4*>(Whh + rp * HDIM + cs);
    const float4* WB = reinterpret_cast<const float4*>(Whh + (rp + 192) * HDIM + cs);
    W6(WDECL) W6(WLOAD) W6(WPIN)

    float* cb = carry + bidx * 2 * HDIM;
    const int e = cs + ((lane < 24) ? lane : 23);
    float hU, cU;
    if (chunk == 0) { hU = h0v[HDIM + e]; cU = c0v[HDIM + e]; }
    else            { hU = cb[e];         cU = cb[HDIM + e]; }

    const float* xpb = xp + (size_t)bidx * T * G4;
    float*       hb1 = h1out + (size_t)bidx * T * HDIM;
    const bool hstore = ((wid % 3) == 0) && (lane < 24);

    float xc0 = 0.f, xc1 = 0.f;
    if (comb) { xc0 = xpb[rp]; xc1 = xpb[rp + 192]; }

#pragma unroll 1
    for (int t = 0; t < T; ++t) {
        float xn0 = 0.f, xn1 = 0.f;
        if (comb && (t + 1 < T)) {
            const float* nx = xpb + (size_t)(t + 1) * G4;
            xn0 = nx[rp];
            xn1 = nx[rp + 192];
        }

        float a0 = comb ? xc0 : 0.f;
        float a1 = comb ? xc1 : 0.f;
        float a0b = 0.f, a1b = 0.f;
        MV_ALL()
        float g0 = a0 + a0b;
        float g1 = a1 + a1b;

        if (!comb) part_sh[colseg - 1][rp] = make_float2(g0, g1);
        __syncthreads();

        if (comb) {
            float2 q0 = part_sh[0][rp], q1 = part_sh[1][rp], q2 = part_sh[2][rp];
            g0 += (q0.x + q1.x) + q2.x;
            g1 += (q0.y + q1.y) + q2.y;
            float s0 = 1.f / (1.f + __expf(-g0));
            if (rp < 96) {
                float tg = 2.f / (1.f + __expf(-2.f * g1)) - 1.f;
                p_sh[rp] = s0 * tg;
            } else {
                float s1 = 1.f / (1.f + __expf(-g1));
                fo_sh[rp - 96] = make_float2(s0, s1);
            }
        }
        __syncthreads();

        float  p  = p_sh[e];
        float2 fo = fo_sh[e];
        cU = fmaf(fo.x, cU, p);
        hU = fo.y * tanh_(cU);

        if (hstore) hb1[(size_t)t * HDIM + e] = hU;
        xc0 = xn0;
        xc1 = xn1;
    }

    if (hstore) { cb[e] = hU; cb[HDIM + e] = cU; }
}

// ---------------------------------------------------------------------------
// Layer-1 input projection (parallel over timesteps), bias folded in.
// ---------------------------------------------------------------------------
#define W24(F) F(0) F(1) F(2) F(3) F(4) F(5) F(6) F(7) F(8) F(9) F(10) F(11) \
               F(12) F(13) F(14) F(15) F(16) F(17) F(18) F(19) F(20) F(21) F(22) F(23)

__global__ __launch_bounds__(384, 1)
void xp_gemm(const float* __restrict__ hin,
             const float* __restrict__ Wih,
             const float* __restrict__ bvec,
             float* __restrict__ xp,
             int t0, int T)
{
    const int TT = 32;
    const int ntb = T / TT;
    const int b  = blockIdx.x / ntb;
    const int tb = blockIdx.x % ntb;
    const int g  = threadIdx.x;

    __shared__ __align__(16) float h_sh[TT * HDIM];

    const float4* W0p = reinterpret_cast<const float4*>(Wih + g * HDIM);
#define XDECL(n) float4 v_##n;
#define XLOAD(n) v_##n = W0p[n];
    W24(XDECL)
    W24(XLOAD)
    const float bias = bvec[g];

    const float* src = hin + ((size_t)b * LSEQ + t0 + (size_t)tb * TT) * HDIM;
    for (int i = g; i < TT * HDIM; i += G4) h_sh[i] = src[i];
    __syncthreads();

    float* dst = xp + ((size_t)b * T + (size_t)tb * TT) * G4 + g;
    for (int tt = 0; tt < TT; ++tt) {
        const float4* h4 = reinterpret_cast<const float4*>(h_sh + tt * HDIM);
        float acc0 = bias, acc1 = 0.f, acc2 = 0.f, acc3 = 0.f;
#define XFMA(n) { float4 hv = h4[n]; \
        acc0 = fmaf(v_##n.x, hv.x, acc0); acc1 = fmaf(v_##n.y, hv.y, acc1); \
        acc2 = fmaf(v_##n.z, hv.z, acc2); acc3 = fmaf(v_##n.w, hv.w, acc3); }
        W24(XFMA)
        dst[(size_t)tt * G4] = (acc0 + acc1) + (acc2 + acc3);
    }
}

// ---------------------------------------------------------------------------
// Head GEMV: out[b][t] = h1[b][t][:] . head_w + head_b
// ---------------------------------------------------------------------------
__global__ __launch_bounds__(256, 1)
void head_gemv(const float* __restrict__ h1,
               const float* __restrict__ head_w,
               const float* __restrict__ head_b,
               float* __restrict__ out,
               int chunk, int T)
{
    const int idx  = blockIdx.x * 4 + (threadIdx.x >> 6);
    const int lane = threadIdx.x & 63;
    const int b = idx / T;
    const int t = idx % T;

    const float* hp = h1 + ((size_t)b * T + t) * HDIM;
    float s = hp[lane] * head_w[lane];
    if (lane < 32) s = fmaf(hp[64 + lane], head_w[64 + lane], s);
    s += __shfl_down(s, 32);
    s += __shfl_down(s, 16);
    s += __shfl_down(s, 8);
    s += __shfl_down(s, 4);
    s += __shfl_down(s, 2);
    s += __shfl_down(s, 1);
    if (lane == 0) out[(size_t)b * LSEQ + (size_t)chunk * T + t] = s + head_b[0];
}

// ---------------------------------------------------------------------------
extern "C" void kernel_launch(void* const* d_in, const int* in_sizes, int n_in,
                              void* d_out, int out_size, void* d_ws, size_t ws_size,
                              hipStream_t stream)
{
    const float* x     = (const float*)d_in[0];
    const float* Wih0  = (const float*)d_in[1];
    const float* Whh0  = (const float*)d_in[2];
    const float* b0    = (const float*)d_in[3];
    const float* Wih1  = (const float*)d_in[4];
    const float* Whh1  = (const float*)d_in[5];
    const float* b1    = (const float*)d_in[6];
    const float* h0    = (const float*)d_in[7];
    const float* c0    = (const float*)d_in[8];
    const float* headw = (const float*)d_in[9];
    const float* headb = (const float*)d_in[10];
    float* out = (float*)d_out;

    char* ws = (char*)d_ws;
    const size_t h0bytes = (size_t)BATCH * LSEQ * HDIM * sizeof(float); // 100.7 MB

    int T = 4096;
    while (T > 512) {
        size_t need = h0bytes
                    + (size_t)T * BATCH * G4 * sizeof(float)
                    + (size_t)T * BATCH * HDIM * sizeof(float)
                    + 8192;
        if (need <= ws_size) break;
        T >>= 1;
    }

    float* h0buf = (float*)ws;
    float* xpbuf = (float*)(ws + h0bytes);
    float* h1buf = (float*)(ws + h0bytes + (size_t)T * BATCH * G4 * sizeof(float));
    float* carry = (float*)(ws + h0bytes + (size_t)T * BATCH * G4 * sizeof(float)
                               + (size_t)T * BATCH * HDIM * sizeof(float));

    lstm_layer0<<<BATCH, 768, 0, stream>>>(x, Wih0, Whh0, b0, h0, c0, h0buf);

    const int nch = LSEQ / T;
    for (int ch = 0; ch < nch; ++ch) {
        xp_gemm<<<BATCH * (T / 32), G4, 0, stream>>>(h0buf, Wih1, b1, xpbuf, ch * T, T);
        lstm_layer1<<<BATCH, 768, 0, stream>>>(xpbuf, Whh1, h0, c0, carry, h1buf, ch, T);
        head_gemv<<<BATCH * T / 4, 256, 0, stream>>>(h1buf, headw, headb, out, ch, T);
    }
}